// Round 4
// baseline (171.272 us; speedup 1.0000x reference)
//
#include <hip/hip_runtime.h>

#define SCALE 8
#define N_ 8
#define C_ 48
#define H_ 48
#define W_ 64
#define WT 16            // w-tile width
#define HO (H_*SCALE)    // 384
#define WO (W_*SCALE)    // 512

typedef float f32x2 __attribute__((ext_vector_type(2)));
typedef float f32x4 __attribute__((ext_vector_type(4)));

// out[n][c][h*8+p][w*8+q] = sum_k softmax_k(mask[n][k*64+p*8+q][h][w]) * inp_pad[n][c][h+di-1][w+dj-1]
// p-split: block owns pg (4 of 8 p rows) of a (n,h,16-wide) tile. Mask planes
// partition exactly across pg (sp = p*8+q), so mask is still read once chip-wide.
__global__ __launch_bounds__(256, 4) void raft_up_kernel(
    const float* __restrict__ inp, const float* __restrict__ mask,
    float* __restrict__ out)
{
    // weights: [q>>1][k][pl][wi] of f32x2 (component = q&1)  -> 18.4 KB
    __shared__ float wgt[4 * 9 * 4 * 16 * 2];
    __shared__ float tin[C_ * 3 * (WT + 2)];   // [c][di][j] 10.1 KB

    const int t = threadIdx.x;
    const int bid = blockIdx.x;          // ((n*48+h)*4 + wblk)*2 + pg
    const int pg   = bid & 1;
    const int wblk = (bid >> 1) & 3;
    const int h    = (bid >> 3) % H_;
    const int n    = bid / (8 * H_);
    const int w0 = wblk * WT;

    // ---- Phase 0: stage input halo tile: tin[c][di][j] = inp[n][c][h+di-1][w0-1+j]
    for (int e = t; e < C_ * 3 * (WT + 2); e += 256) {
        int c   = e / (3 * (WT + 2));
        int rem = e % (3 * (WT + 2));
        int di  = rem / (WT + 2);
        int j   = rem % (WT + 2);
        int row = h + di - 1;
        int col = w0 - 1 + j;
        float v = 0.f;
        if (row >= 0 && row < H_ && col >= 0 && col < W_)
            v = inp[(((size_t)n * C_ + c) * H_ + row) * W_ + col];
        tin[e] = v;
    }

    // ---- Phase 1: 512 softmaxes (32 sp x 16 wi), 2 per thread; wi fastest -> coalesced
    #pragma unroll
    for (int r = 0; r < 2; ++r) {
        int id  = r * 256 + t;
        int wi  = id & (WT - 1);
        int spl = id >> 4;               // 0..31 local sp
        int pl  = spl >> 3;              // 0..3
        int q   = spl & 7;
        int spg = pg * 32 + spl;         // global sp = (pg*4+pl)*8 + q
        const float* mp = mask + (size_t)n * 576 * H_ * W_
                               + (size_t)spg * H_ * W_
                               + (size_t)h * W_ + w0 + wi;
        float v[9];
        float mx = -1e30f;
        #pragma unroll
        for (int k = 0; k < 9; ++k) {
            float x = mp[(size_t)k * 64 * H_ * W_];
            v[k] = x;
            mx = fmaxf(mx, x);
        }
        float s = 0.f;
        #pragma unroll
        for (int k = 0; k < 9; ++k) { v[k] = __expf(v[k] - mx); s += v[k]; }
        float inv = 1.f / s;
        #pragma unroll
        for (int k = 0; k < 9; ++k)
            wgt[((((q >> 1) * 9 + k) * 4 + pl) * 16 + wi) * 2 + (q & 1)] = v[k] * inv;
    }
    __syncthreads();

    // ---- Phase 2: thread owns (qq, wi) = 4 consecutive output columns; 6 channels
    const int lane5 = t & 31;
    const int qq = lane5 & 1;        // q quad
    const int wi = lane5 >> 1;       // 0..15
    const int cg = t >> 5;           // 0..7
    const int c0 = cg * 6;

    float taps[6][9];                // loaded once; address depends only on wi
    #pragma unroll
    for (int cc = 0; cc < 6; ++cc)
        #pragma unroll
        for (int di = 0; di < 3; ++di)
            #pragma unroll
            for (int dj = 0; dj < 3; ++dj)
                taps[cc][di * 3 + dj] = tin[((c0 + cc) * 3 + di) * (WT + 2) + wi + dj];

    float* outb = out + (((size_t)(n * C_ + c0)) * HO + h * SCALE + pg * 4) * WO
                      + (size_t)w0 * SCALE + wi * 8 + qq * 4;

    #pragma unroll
    for (int pl = 0; pl < 4; ++pl) {
        f32x4 acc[6] = {};
        #pragma unroll
        for (int k = 0; k < 9; ++k) {
            f32x2 a = *(const f32x2*)&wgt[(((qq * 2 + 0) * 9 + k) * 4 + pl) * 32 + wi * 2];
            f32x2 b = *(const f32x2*)&wgt[(((qq * 2 + 1) * 9 + k) * 4 + pl) * 32 + wi * 2];
            #pragma unroll
            for (int cc = 0; cc < 6; ++cc) {
                float tp = taps[cc][k];
                acc[cc].x = fmaf(a.x, tp, acc[cc].x);
                acc[cc].y = fmaf(a.y, tp, acc[cc].y);
                acc[cc].z = fmaf(b.x, tp, acc[cc].z);
                acc[cc].w = fmaf(b.y, tp, acc[cc].w);
            }
        }
        #pragma unroll
        for (int cc = 0; cc < 6; ++cc)
            *(f32x4*)(outb + ((size_t)cc * HO + pl) * WO) = acc[cc];
    }
}

extern "C" void kernel_launch(void* const* d_in, const int* in_sizes, int n_in,
                              void* d_out, int out_size, void* d_ws, size_t ws_size,
                              hipStream_t stream) {
    const float* inp  = (const float*)d_in[0];
    const float* mask = (const float*)d_in[1];
    float* out = (float*)d_out;
    const int blocks = N_ * H_ * (W_ / WT) * 2;  // 8*48*4*2 = 3072
    raft_up_kernel<<<blocks, 256, 0, stream>>>(inp, mask, out);
}

// Round 5
// 96.839 us; speedup vs baseline: 1.7686x; 1.7686x over previous
//
#include <hip/hip_runtime.h>

#define N_ 8
#define C_ 48
#define H_ 48
#define W_ 64
#define HO 384
#define WO 512
#define HW (H_*W_)   // 3072
#define CP 52        // padded channel dim in tin (mult of 4 for b128 alignment)

typedef float f32x4 __attribute__((ext_vector_type(4)));

// out[n][c][h*8+p][w*8+q] = sum_k softmax_k(mask[n][k*64+p*8+q][h][w]) * inp_pad[n][c][h+di-1][w+dj-1]
// Block = (n, h, pg), pg in 0..3 owns p = {2pg, 2pg+1}; full W row (mask rows
// are 256B, aligned, read by exactly one block -> mask fetched once chip-wide).
__global__ __launch_bounds__(256, 2) void raft_up_kernel(
    const float* __restrict__ inp, const float* __restrict__ mask,
    float* __restrict__ out)
{
    __shared__ float tin[3 * 66 * CP];        // [di][j=w+1][c]   41,184 B
    __shared__ float wgt[9 * 2 * 8 * 64];     // [k][pl][q][wi]   36,864 B

    const int t = threadIdx.x;
    const int bid = blockIdx.x;               // (n*H + h)*4 + pg
    const int pg = bid & 3;
    const int h  = (bid >> 2) % H_;
    const int n  = bid / (4 * H_);

    // ---- Phase 0: tin[di][j][c] = inp[n][c][h+di-1][j-1]  (zero-pad OOB)
    // flat e = (di*C + c)*66 + j, j fastest across lanes -> coalesced reads
    for (int e = t; e < 3 * C_ * 66; e += 256) {
        int j   = e % 66;
        int dc  = e / 66;
        int c   = dc % C_;
        int di  = dc / C_;
        int row = h + di - 1;
        int col = j - 1;
        float v = 0.f;
        if (row >= 0 && row < H_ && col >= 0 && col < W_)
            v = inp[((n * C_ + c) * H_ + row) * W_ + col];
        tin[(di * 66 + j) * CP + c] = v;
    }

    // ---- Phase 1: 16 planes x 64 wi softmaxes, 4 wi per thread (f32x4)
    {
        const int spl = t >> 4;               // 0..15  (pl*8 + q)
        const int wi4 = (t & 15) * 4;         // 0,4,...,60
        const int pl = spl >> 3, q = spl & 7;
        const int p  = pg * 2 + pl;
        const float* mp = mask + ((size_t)n * 576 + (size_t)(p * 8 + q)) * HW
                               + h * W_ + wi4;
        f32x4 v[9];
        f32x4 mx;
        #pragma unroll
        for (int k = 0; k < 9; ++k) {
            v[k] = *(const f32x4*)(mp + (size_t)k * 64 * HW);
            if (k == 0) mx = v[0];
            else {
                mx.x = fmaxf(mx.x, v[k].x); mx.y = fmaxf(mx.y, v[k].y);
                mx.z = fmaxf(mx.z, v[k].z); mx.w = fmaxf(mx.w, v[k].w);
            }
        }
        f32x4 s = (f32x4){0.f, 0.f, 0.f, 0.f};
        #pragma unroll
        for (int k = 0; k < 9; ++k) {
            v[k].x = __expf(v[k].x - mx.x); v[k].y = __expf(v[k].y - mx.y);
            v[k].z = __expf(v[k].z - mx.z); v[k].w = __expf(v[k].w - mx.w);
            s += v[k];
        }
        f32x4 inv;
        inv.x = 1.f / s.x; inv.y = 1.f / s.y; inv.z = 1.f / s.z; inv.w = 1.f / s.w;
        #pragma unroll
        for (int k = 0; k < 9; ++k)
            *(f32x4*)&wgt[((k * 2 + pl) * 8 + q) * 64 + wi4] = v[k] * inv;
    }
    __syncthreads();

    // ---- Phase 2: thread owns 4 output floats of each row: col = tq*4 + (0..3)
    const int tq    = t & 127;       // two waves cover a full 2048B row
    const int chalf = t >> 7;        // channels 0-23 / 24-47
    const int q4    = tq & 1;        // q quad: q = q4*4 + j
    const int wi    = tq >> 1;       // 0..63  (w coordinate)

    // weights for my (q-quad, wi), both pl, all k: held in 72 VGPRs
    f32x4 w[2][9];
    #pragma unroll
    for (int pl = 0; pl < 2; ++pl)
        #pragma unroll
        for (int k = 0; k < 9; ++k) {
            const float* wp = &wgt[((k * 2 + pl) * 8 + q4 * 4) * 64 + wi];
            w[pl][k] = (f32x4){wp[0], wp[64], wp[128], wp[192]};
        }

    float* outb = out + ((size_t)n * C_ * HO + h * 8 + pg * 2) * WO + tq * 4;

    for (int cblk = 0; cblk < 6; ++cblk) {
        const int c0 = chalf * 24 + cblk * 4;
        f32x4 taps[9];                        // c-vectors (4 channels)
        #pragma unroll
        for (int di = 0; di < 3; ++di)
            #pragma unroll
            for (int dj = 0; dj < 3; ++dj)
                taps[di * 3 + dj] = *(const f32x4*)&tin[(di * 66 + wi + dj) * CP + c0];
        #pragma unroll
        for (int pl = 0; pl < 2; ++pl) {
            #pragma unroll
            for (int cc = 0; cc < 4; ++cc) {
                f32x4 acc = (f32x4){0.f, 0.f, 0.f, 0.f};
                #pragma unroll
                for (int k = 0; k < 9; ++k) {
                    const float tp = taps[k][cc];   // channel c0+cc, tap k
                    acc += w[pl][k] * tp;
                }
                *(f32x4*)(outb + ((size_t)(c0 + cc) * HO + pl) * WO) = acc;
            }
        }
    }
}

extern "C" void kernel_launch(void* const* d_in, const int* in_sizes, int n_in,
                              void* d_out, int out_size, void* d_ws, size_t ws_size,
                              hipStream_t stream) {
    const float* inp  = (const float*)d_in[0];
    const float* mask = (const float*)d_in[1];
    float* out = (float*)d_out;
    const int blocks = N_ * H_ * 4;   // 8*48*4 = 1536
    raft_up_kernel<<<blocks, 256, 0, stream>>>(inp, mask, out);
}

// Round 6
// 90.878 us; speedup vs baseline: 1.8846x; 1.0656x over previous
//
#include <hip/hip_runtime.h>

#define N_ 8
#define C_ 48
#define H_ 48
#define W_ 64
#define HO 384
#define WO 512
#define HW (H_*W_)   // 3072

typedef float f32x4 __attribute__((ext_vector_type(4)));

// out[n][c][h*8+p][w*8+q] = sum_k softmax_k(mask[n][k*64+p*8+q][h][w]) * inp_pad[n][c][h+di-1][w+dj-1]
// Zero-LDS design: block = (n, h, pg); pg owns p = {2pg, 2pg+1}.
// Thread (chalf, q4, wi) computes its own softmax weights into registers
// (mask rows are 256B-aligned, each read by exactly one block -> read-once),
// reads taps straight from L2-resident inp, writes 16B/lane contiguous rows.
// No __syncthreads anywhere -> loads/stores of all waves freely interleave.
__global__ __launch_bounds__(256, 3) void raft_up_kernel(
    const float* __restrict__ inp, const float* __restrict__ mask,
    float* __restrict__ out)
{
    const int t   = threadIdx.x;
    const int bid = blockIdx.x;            // (n*H + h)*4 + pg
    const int pg  = bid & 3;
    const int h   = (bid >> 2) % H_;
    const int n   = bid / (4 * H_);

    const int tq    = t & 127;
    const int chalf = t >> 7;              // 0: c 0..23, 1: c 24..47
    const int q4    = tq & 1;              // q quad (q = q4*4 + j)
    const int wi    = tq >> 1;             // 0..63 (w coordinate)

    // ---- softmax over 9 taps for my 8 planes (pl x 4 q's); f32x4 lanes = j (q)
    // global mask channel = k*64 + (pg*2+pl)*8 + q4*4 + j
    f32x4 w[2][9];
    {
        const float* mb = mask + ((size_t)n * 576 + pg * 16 + q4 * 4) * HW
                               + h * W_ + wi;
        #pragma unroll
        for (int pl = 0; pl < 2; ++pl)
            #pragma unroll
            for (int k = 0; k < 9; ++k)
                #pragma unroll
                for (int j = 0; j < 4; ++j)
                    w[pl][k][j] = mb[(size_t)(k * 64 + pl * 8 + j) * HW];

        #pragma unroll
        for (int pl = 0; pl < 2; ++pl) {
            f32x4 mx = w[pl][0];
            #pragma unroll
            for (int k = 1; k < 9; ++k) {
                mx.x = fmaxf(mx.x, w[pl][k].x); mx.y = fmaxf(mx.y, w[pl][k].y);
                mx.z = fmaxf(mx.z, w[pl][k].z); mx.w = fmaxf(mx.w, w[pl][k].w);
            }
            f32x4 s = (f32x4){0.f, 0.f, 0.f, 0.f};
            #pragma unroll
            for (int k = 0; k < 9; ++k) {
                f32x4 e;
                e.x = __expf(w[pl][k].x - mx.x);
                e.y = __expf(w[pl][k].y - mx.y);
                e.z = __expf(w[pl][k].z - mx.z);
                e.w = __expf(w[pl][k].w - mx.w);
                w[pl][k] = e;
                s += e;
            }
            f32x4 inv;
            inv.x = 1.f / s.x; inv.y = 1.f / s.y;
            inv.z = 1.f / s.z; inv.w = 1.f / s.w;
            #pragma unroll
            for (int k = 0; k < 9; ++k) w[pl][k] *= inv;
        }
    }

    // ---- tap validity (zero padding)
    const bool rok0 = (h >= 1), rok2 = (h <= H_ - 2);
    const bool cok0 = (wi >= 1), cok2 = (wi <= W_ - 2);
    const bool ok[3][3] = {
        { rok0 && cok0, rok0, rok0 && cok2 },
        { cok0,         true, cok2         },
        { rok2 && cok0, rok2, rok2 && cok2 },
    };

    const float* ib = inp + (size_t)(n * C_ + chalf * 24) * HW + (wi - 1);
    float* outb = out + ((size_t)(n * C_ + chalf * 24) * HO + h * 8 + pg * 2) * WO
                      + wi * 8 + q4 * 4;

    for (int cblk = 0; cblk < 6; ++cblk) {
        // taps for 4 channels, read straight from L2-resident inp
        float tp[4][9];
        #pragma unroll
        for (int di = 0; di < 3; ++di)
            #pragma unroll
            for (int dj = 0; dj < 3; ++dj) {
                const bool o = ok[di][dj];
                #pragma unroll
                for (int cc = 0; cc < 4; ++cc) {
                    const float* p = ib + (size_t)((cblk * 4 + cc) * H_ + h - 1 + di) * W_ + dj;
                    tp[cc][di * 3 + dj] = o ? *p : 0.f;
                }
            }
        #pragma unroll
        for (int cc = 0; cc < 4; ++cc)
            #pragma unroll
            for (int pl = 0; pl < 2; ++pl) {
                f32x4 acc = w[pl][0] * tp[cc][0];
                #pragma unroll
                for (int k = 1; k < 9; ++k)
                    acc += w[pl][k] * tp[cc][k];
                *(f32x4*)(outb + ((size_t)(cblk * 4 + cc) * HO + pl) * WO) = acc;
            }
    }
}

extern "C" void kernel_launch(void* const* d_in, const int* in_sizes, int n_in,
                              void* d_out, int out_size, void* d_ws, size_t ws_size,
                              hipStream_t stream) {
    const float* inp  = (const float*)d_in[0];
    const float* mask = (const float*)d_in[1];
    float* out = (float*)d_out;
    const int blocks = N_ * H_ * 4;   // 8*48*4 = 1536
    raft_up_kernel<<<blocks, 256, 0, stream>>>(inp, mask, out);
}